// Round 12
// baseline (377.432 us; speedup 1.0000x reference)
//
#include <hip/hip_runtime.h>
#include <hip/hip_bf16.h>

typedef short s8v __attribute__((ext_vector_type(8)));
typedef float f4v __attribute__((ext_vector_type(4)));
typedef unsigned short u16;
typedef unsigned int u32;

#define PI_HALF 1.57079632679489662f

// ---------------------------------------------------------------------------
// Prep: repack weights into d_ws (unchanged, verified R1-R11).
// ---------------------------------------------------------------------------
__global__ void prep_kernel(const float* __restrict__ W1,
                            const float* __restrict__ W2,
                            const float* __restrict__ W3,
                            const float* __restrict__ W4,
                            u16* __restrict__ w3f,
                            u16* __restrict__ w4f,
                            float* __restrict__ w1t,
                            float* __restrict__ w2c) {
  int i = blockIdx.x * 256 + threadIdx.x;
  if (i < 65536) {
    int j = i & 7, lane = (i >> 3) & 63, kk = (i >> 9) & 7, ntg = i >> 12;
    int k = kk * 32 + (lane >> 4) * 8 + j;
    int n = ntg * 16 + (lane & 15);
    __hip_bfloat16 v = __float2bfloat16(W3[k * 256 + n]);
    w3f[i] = *(u16*)&v;
  } else if (i < 65536 + 131072) {
    int t = i - 65536;
    int j = t & 7, lane = (t >> 3) & 63, kk = (t >> 9) & 7, ntg = t >> 12;
    int k = kk * 32 + (lane >> 4) * 8 + j;
    int n = ntg * 16 + (lane & 15);
    __hip_bfloat16 v = __float2bfloat16(W4[k * 512 + n]);
    w4f[t] = *(u16*)&v;
  } else if (i < 65536 + 131072 + 2048) {
    int t = i - (65536 + 131072);
    int k = t >> 3, j = t & 7;
    w1t[t] = W1[j * 256 + k];
  } else if (i < 65536 + 131072 + 4096) {
    int t = i - (65536 + 131072 + 2048);
    int k = t >> 3, q = t & 7;
    w2c[t] = W2[k * 256 + q];
  }
}

// ---------------------------------------------------------------------------
// k1: per-row MLP front-end, split-K 4 threads/row (R2-R4's PASSED math:
// partial e over 64 k-values, shfl_xor(1)+(2) quad reduce, +b2, relu, sincos).
// 64 rows/block of 256 threads -> 2048 blocks -> 8 waves/SIMD occupancy
// (vs 1-thread/row's 2/SIMD latency-bound chain). Thread kc writes float4
// #kc of the 64B cs row: op[0]=cc0..3, op[1]=cc4..7, op[2]=ss0..3,
// op[3]=ss4..7 -- fully coalesced.
// ---------------------------------------------------------------------------
__global__ __launch_bounds__(256, 2)
void angle_kernel(const float* __restrict__ x,
                  const float* __restrict__ b1v,
                  const float* __restrict__ b2v,
                  const float* __restrict__ w1t,
                  const float* __restrict__ w2c,
                  float* __restrict__ cs, int B) {
  const int tid = threadIdx.x;
  const int rl  = tid >> 2;          // local row 0..63
  const int kc  = tid & 3;           // k-chunk 0..3
  const int r   = blockIdx.x * 64 + rl;
  if (r >= B) return;                // whole quad exits together
  float xv[8];
  {
    const float4* xp = (const float4*)(x + (size_t)r * 8);
    float4 a = xp[0], b = xp[1];
    xv[0] = a.x; xv[1] = a.y; xv[2] = a.z; xv[3] = a.w;
    xv[4] = b.x; xv[5] = b.y; xv[6] = b.z; xv[7] = b.w;
  }
  float e[8];
#pragma unroll
  for (int q = 0; q < 8; q++) e[q] = 0.f;
  const int kbase = kc * 64;
#pragma unroll 4
  for (int ki = 0; ki < 64; ki++) {
    const int k = kbase + ki;
    const float4* wp = (const float4*)(w1t + k * 8);
    float4 wa = wp[0], wb = wp[1];
    float h = b1v[k];
    h = fmaf(xv[0], wa.x, h); h = fmaf(xv[1], wa.y, h);
    h = fmaf(xv[2], wa.z, h); h = fmaf(xv[3], wa.w, h);
    h = fmaf(xv[4], wb.x, h); h = fmaf(xv[5], wb.y, h);
    h = fmaf(xv[6], wb.z, h); h = fmaf(xv[7], wb.w, h);
    h = fmaxf(h, 0.f);
    const float4* w2p = (const float4*)(w2c + k * 8);
    float4 ya = w2p[0], yb = w2p[1];
    e[0] = fmaf(h, ya.x, e[0]); e[1] = fmaf(h, ya.y, e[1]);
    e[2] = fmaf(h, ya.z, e[2]); e[3] = fmaf(h, ya.w, e[3]);
    e[4] = fmaf(h, yb.x, e[4]); e[5] = fmaf(h, yb.y, e[5]);
    e[6] = fmaf(h, yb.z, e[6]); e[7] = fmaf(h, yb.w, e[7]);
  }
  // quad reduce (lanes rl*4+kc share a row; xor 1,2 stays in-quad)
#pragma unroll
  for (int q = 0; q < 8; q++) {
    e[q] += __shfl_xor(e[q], 1);
    e[q] += __shfl_xor(e[q], 2);
  }
  float cc[8], ss[8];
#pragma unroll
  for (int q = 0; q < 8; q++) {
    float ang = fmaxf(e[q] + b2v[q], 0.f) * PI_HALF;
    ss[q] = __sinf(ang);
    cc[q] = __cosf(ang);
  }
  float4 v;
  if (kc == 0)      v = (float4){cc[0], cc[1], cc[2], cc[3]};
  else if (kc == 1) v = (float4){cc[4], cc[5], cc[6], cc[7]};
  else if (kc == 2) v = (float4){ss[0], ss[1], ss[2], ss[3]};
  else              v = (float4){ss[4], ss[5], ss[6], ss[7]};
  ((float4*)(cs + (size_t)r * 16))[kc] = v;
}

// ---------------------------------------------------------------------------
// k2: GEMM kernel -- R11's PASSED logic byte-identical except
// __launch_bounds__(256,4): cap = 512/4 = 128 total regs/wave. Feasible:
// stage peak ~40 arch, GEMM peak ~28 arch + 64 AGPR (shared acc[4][4]) =
// ~128 -> 4 waves/SIMD -> 16 waves/CU = 4 blocks (R11: 140 -> 12 waves).
// If the allocator can't fit 64 arch it spills a few regs (numerics-safe,
// R2-R4 precedent) -- detectable as FETCH/WRITE inflation; revert if so.
// ---------------------------------------------------------------------------
__global__ __launch_bounds__(256, 4)
void gemm_kernel(const float* __restrict__ cs,
                 const float* __restrict__ b3v,
                 const float* __restrict__ b4v,
                 const u16* __restrict__ w3f,
                 const u16* __restrict__ w4f,
                 float* __restrict__ out, int B) {
  __shared__ alignas(16) u16 st[64 * 256];   // 32 KB: state tile, then f tile
  const int tid = threadIdx.x;
  const int row0 = blockIdx.x * 64;

  // ---------------- stage: cs -> state tile in LDS (4 threads/row) -------
  {
    const int rl = tid >> 2;          // local row 0..63
    const int s  = tid & 3;           // 4 threads/row: covers e in [64s,64s+64)
    const int r  = row0 + rl;
    float4 ca, cb, sa, sb;            // cc[0..3], cc[4..7], ss[0..3], ss[4..7]
    if (r < B) {
      const float4* ip = (const float4*)(cs + (size_t)r * 16);
      ca = ip[0]; cb = ip[1]; sa = ip[2]; sb = ip[3];
    } else {
      ca = cb = sa = sb = (float4){0.f, 0.f, 0.f, 0.f};
    }
    // qubits 0,1 from s bits (b0 = s&2, b1 = s&1)
    float q0 = (s & 2) ? sa.x : ca.x;
    float q1 = (s & 1) ? sa.y : ca.y;
    float p01 = q0 * q1;
    // A8 over qubits 2,3,4 (index it = b2b3b4)
    float A8[8];
    {
      float c2 = ca.z, s2 = sa.z, c3 = ca.w, s3 = sa.w, c4 = cb.x, s4 = sb.x;
      float p23[4];
      p23[0] = c2 * c3; p23[1] = c2 * s3; p23[2] = s2 * c3; p23[3] = s2 * s3;
#pragma unroll
      for (int m = 0; m < 4; m++) {
        A8[2*m]   = p01 * p23[m] * c4;
        A8[2*m+1] = p01 * p23[m] * s4;
      }
    }
    // L8 over qubits 5,6,7 (index j = b5b6b7)
    float L8[8];
    {
      float c5 = cb.y, s5 = sb.y, c6 = cb.z, s6 = sb.z, c7 = cb.w, s7 = sb.w;
      float p56[4];
      p56[0] = c5 * c6; p56[1] = c5 * s6; p56[2] = s5 * c6; p56[3] = s5 * s6;
#pragma unroll
      for (int m = 0; m < 4; m++) {
        L8[2*m]   = p56[m] * c7;
        L8[2*m+1] = p56[m] * s7;
      }
    }
    // write 8 groups of 16B (64 bf16 = this thread's quarter of the row)
#pragma unroll
    for (int it = 0; it < 8; it++) {
      float ah = A8[it];                   // static index
      union { u16 h8[8]; uint4 u4; } pk;
#pragma unroll
      for (int j = 0; j < 8; j++) {
        __hip_bfloat16 bv = __float2bfloat16(ah * L8[j]);
        pk.h8[j] = *(u16*)&bv;
      }
      u32 byte = (u32)(rl * 512 + (s * 8 + it) * 16) ^ (u32)((rl & 7) << 4);
      *(uint4*)((char*)st + byte) = pk.u4;
    }
  }
  __syncthreads();

  // ---------------- wave/tile decomposition (R2's passed shape) ----------
  const int lane = tid & 63;
  const int wn   = tid >> 6;      // 0..3 -> N slice (all 64 rows per wave)
  const int lr   = lane & 15;
  const int lg   = lane >> 4;

  f4v acc[4][4];                  // SHARED accumulator for GEMM A and B

  // ---------------- GEMM A: f = relu(state @ W3 + b3) ----------------
#pragma unroll
  for (int nt = 0; nt < 4; nt++)
#pragma unroll
    for (int mt = 0; mt < 4; mt++) acc[nt][mt] = (f4v){0.f, 0.f, 0.f, 0.f};

  for (int kk = 0; kk < 8; kk++) {
    s8v a[4];
#pragma unroll
    for (int mt = 0; mt < 4; mt++) {
      int row = mt * 16 + lr;
      u32 byte = (u32)(row * 512 + kk * 64 + lg * 16) ^ (u32)((row & 7) << 4);
      a[mt] = *(const s8v*)((const char*)st + byte);
    }
#pragma unroll
    for (int nt = 0; nt < 4; nt++) {
      int ntg = wn * 4 + nt;
      s8v b = ((const s8v*)w3f)[(ntg * 8 + kk) * 64 + lane];
#pragma unroll
      for (int mt = 0; mt < 4; mt++)
        acc[nt][mt] = __builtin_amdgcn_mfma_f32_16x16x32_bf16(a[mt], b, acc[nt][mt], 0, 0, 0);
    }
  }
  __syncthreads();                 // all state reads complete before overwrite

  // f (bf16) overwrites state tile in place
#pragma unroll
  for (int nt = 0; nt < 4; nt++) {
    int col = wn * 64 + nt * 16 + lr;
    float bias = b3v[col];
#pragma unroll
    for (int mt = 0; mt < 4; mt++) {
#pragma unroll
      for (int i = 0; i < 4; i++) {
        int row = mt * 16 + lg * 4 + i;
        float v = fmaxf(acc[nt][mt][i] + bias, 0.f);
        __hip_bfloat16 bv = __float2bfloat16(v);
        u32 byte = (u32)(row * 512 + col * 2) ^ (u32)((row & 7) << 4);
        *(u16*)((char*)st + byte) = *(u16*)&bv;
      }
    }
  }
  __syncthreads();

  // ---------------- GEMM B: out = f @ W4 + b4 (two 64-col chunks) -------
#pragma unroll 1
  for (int nh = 0; nh < 2; nh++) {
    const int nbase = wn * 128 + nh * 64;
#pragma unroll
    for (int nt = 0; nt < 4; nt++)
#pragma unroll
      for (int mt = 0; mt < 4; mt++) acc[nt][mt] = (f4v){0.f, 0.f, 0.f, 0.f};

    for (int kk = 0; kk < 8; kk++) {
      s8v a[4];
#pragma unroll
      for (int mt = 0; mt < 4; mt++) {
        int row = mt * 16 + lr;
        u32 byte = (u32)(row * 512 + kk * 64 + lg * 16) ^ (u32)((row & 7) << 4);
        a[mt] = *(const s8v*)((const char*)st + byte);
      }
#pragma unroll
      for (int nt = 0; nt < 4; nt++) {
        int ntg = (nbase >> 4) + nt;
        s8v b = ((const s8v*)w4f)[(ntg * 8 + kk) * 64 + lane];
#pragma unroll
        for (int mt = 0; mt < 4; mt++)
          acc[nt][mt] = __builtin_amdgcn_mfma_f32_16x16x32_bf16(a[mt], b, acc[nt][mt], 0, 0, 0);
      }
    }
    // store fp32 + bias
#pragma unroll
    for (int nt = 0; nt < 4; nt++) {
      int col = nbase + nt * 16 + lr;
      float bias = b4v[col];
#pragma unroll
      for (int mt = 0; mt < 4; mt++) {
        int rowg = row0 + mt * 16 + lg * 4;
        if (rowg + 3 < B) {
          float* op = out + (size_t)rowg * 512 + col;
          op[0]    = acc[nt][mt][0] + bias;
          op[512]  = acc[nt][mt][1] + bias;
          op[1024] = acc[nt][mt][2] + bias;
          op[1536] = acc[nt][mt][3] + bias;
        } else {
#pragma unroll
          for (int i = 0; i < 4; i++)
            if (rowg + i < B) out[(size_t)(rowg + i) * 512 + col] = acc[nt][mt][i] + bias;
        }
      }
    }
  }
}

extern "C" void kernel_launch(void* const* d_in, const int* in_sizes, int n_in,
                              void* d_out, int out_size, void* d_ws, size_t ws_size,
                              hipStream_t stream) {
  const float* x  = (const float*)d_in[0];
  const float* W1 = (const float*)d_in[1];
  const float* b1 = (const float*)d_in[2];
  const float* W2 = (const float*)d_in[3];
  const float* b2 = (const float*)d_in[4];
  const float* W3 = (const float*)d_in[5];
  const float* b3 = (const float*)d_in[6];
  const float* W4 = (const float*)d_in[7];
  const float* b4 = (const float*)d_in[8];
  float* out = (float*)d_out;
  const int B = in_sizes[0] / 8;

  u16*   w3f = (u16*)d_ws;                                        // 128 KB
  u16*   w4f = (u16*)((char*)d_ws + 131072);                      // 256 KB
  float* w1t = (float*)((char*)d_ws + 131072 + 262144);           //   8 KB
  float* w2c = (float*)((char*)d_ws + 131072 + 262144 + 8192);    //   8 KB
  float* cs  = (float*)((char*)d_ws + 131072 + 262144 + 16384);   // B*64 B

  prep_kernel<<<784, 256, 0, stream>>>(W1, W2, W3, W4, w3f, w4f, w1t, w2c);
  angle_kernel<<<(B + 63) / 64, 256, 0, stream>>>(x, b1, b2, w1t, w2c, cs, B);
  gemm_kernel<<<(B + 63) / 64, 256, 0, stream>>>(cs, b3, b4, w3f, w4f, out, B);
}

// Round 14
// 181.429 us; speedup vs baseline: 2.0803x; 2.0803x over previous
//
#include <hip/hip_runtime.h>
#include <hip/hip_bf16.h>

typedef short s8v __attribute__((ext_vector_type(8)));
typedef float f4v __attribute__((ext_vector_type(4)));
typedef unsigned short u16;
typedef unsigned int u32;

#define PI_HALF 1.57079632679489662f

// ---------------------------------------------------------------------------
// Prep: repack weights into d_ws (unchanged, verified R1-R13).
// ---------------------------------------------------------------------------
__global__ void prep_kernel(const float* __restrict__ W1,
                            const float* __restrict__ W2,
                            const float* __restrict__ W3,
                            const float* __restrict__ W4,
                            u16* __restrict__ w3f,
                            u16* __restrict__ w4f,
                            float* __restrict__ w1t,
                            float* __restrict__ w2c) {
  int i = blockIdx.x * 256 + threadIdx.x;
  if (i < 65536) {
    int j = i & 7, lane = (i >> 3) & 63, kk = (i >> 9) & 7, ntg = i >> 12;
    int k = kk * 32 + (lane >> 4) * 8 + j;
    int n = ntg * 16 + (lane & 15);
    __hip_bfloat16 v = __float2bfloat16(W3[k * 256 + n]);
    w3f[i] = *(u16*)&v;
  } else if (i < 65536 + 131072) {
    int t = i - 65536;
    int j = t & 7, lane = (t >> 3) & 63, kk = (t >> 9) & 7, ntg = t >> 12;
    int k = kk * 32 + (lane >> 4) * 8 + j;
    int n = ntg * 16 + (lane & 15);
    __hip_bfloat16 v = __float2bfloat16(W4[k * 512 + n]);
    w4f[t] = *(u16*)&v;
  } else if (i < 65536 + 131072 + 2048) {
    int t = i - (65536 + 131072);
    int k = t >> 3, j = t & 7;
    w1t[t] = W1[j * 256 + k];
  } else if (i < 65536 + 131072 + 4096) {
    int t = i - (65536 + 131072 + 2048);
    int k = t >> 3, q = t & 7;
    w2c[t] = W2[k * 256 + q];
  }
}

// ---------------------------------------------------------------------------
// k1: per-row MLP front-end. 1 thread/row. Writes cs[r*16] = {cc[0..7],
// ss[0..7]} as f32. (R11-verbatim; passed.)
// ---------------------------------------------------------------------------
__global__ void angle_kernel(const float* __restrict__ x,
                             const float* __restrict__ b1v,
                             const float* __restrict__ b2v,
                             const float* __restrict__ w1t,
                             const float* __restrict__ w2c,
                             float* __restrict__ cs, int B) {
  const int r = blockIdx.x * 256 + threadIdx.x;
  if (r >= B) return;
  float xv[8];
  {
    const float4* xp = (const float4*)(x + (size_t)r * 8);
    float4 a = xp[0], b = xp[1];
    xv[0] = a.x; xv[1] = a.y; xv[2] = a.z; xv[3] = a.w;
    xv[4] = b.x; xv[5] = b.y; xv[6] = b.z; xv[7] = b.w;
  }
  float e[8];
#pragma unroll
  for (int q = 0; q < 8; q++) e[q] = b2v[q];
#pragma unroll 4
  for (int k = 0; k < 256; k++) {
    const float4* wp = (const float4*)(w1t + k * 8);
    float4 wa = wp[0], wb = wp[1];
    float h = b1v[k];
    h = fmaf(xv[0], wa.x, h); h = fmaf(xv[1], wa.y, h);
    h = fmaf(xv[2], wa.z, h); h = fmaf(xv[3], wa.w, h);
    h = fmaf(xv[4], wb.x, h); h = fmaf(xv[5], wb.y, h);
    h = fmaf(xv[6], wb.z, h); h = fmaf(xv[7], wb.w, h);
    h = fmaxf(h, 0.f);
    const float4* w2p = (const float4*)(w2c + k * 8);
    float4 ya = w2p[0], yb = w2p[1];
    e[0] = fmaf(h, ya.x, e[0]); e[1] = fmaf(h, ya.y, e[1]);
    e[2] = fmaf(h, ya.z, e[2]); e[3] = fmaf(h, ya.w, e[3]);
    e[4] = fmaf(h, yb.x, e[4]); e[5] = fmaf(h, yb.y, e[5]);
    e[6] = fmaf(h, yb.z, e[6]); e[7] = fmaf(h, yb.w, e[7]);
  }
  float cc[8], ss[8];
#pragma unroll
  for (int q = 0; q < 8; q++) {
    float ang = fmaxf(e[q], 0.f) * PI_HALF;
    ss[q] = __sinf(ang);
    cc[q] = __cosf(ang);
  }
  float4* op = (float4*)(cs + (size_t)r * 16);
  op[0] = (float4){cc[0], cc[1], cc[2], cc[3]};
  op[1] = (float4){cc[4], cc[5], cc[6], cc[7]};
  op[2] = (float4){ss[0], ss[1], ss[2], ss[3]};
  op[3] = (float4){ss[4], ss[5], ss[6], ss[7]};
}

// ---------------------------------------------------------------------------
// k2: GEMM kernel. 64 rows/block, 256 threads (4 waves), 32 KB LDS.
// R11-verbatim (passed at 181 us): launch_bounds(256,2), shared acc[4][4],
// stage 4 threads/row fully static, GEMM A -> f in-place -> GEMM B.
// NOTE (R9/R10/R13): higher-occupancy variants of this kernel failed
// numerics NONDETERMINISTICALLY (a few f-elements wrong by O(0.1)); this
// configuration is the verified-passing one -- do not push min_waves=4.
// ---------------------------------------------------------------------------
__global__ __launch_bounds__(256, 2)
void gemm_kernel(const float* __restrict__ cs,
                 const float* __restrict__ b3v,
                 const float* __restrict__ b4v,
                 const u16* __restrict__ w3f,
                 const u16* __restrict__ w4f,
                 float* __restrict__ out, int B) {
  __shared__ alignas(16) u16 st[64 * 256];   // 32 KB: state tile, then f tile
  const int tid = threadIdx.x;
  const int row0 = blockIdx.x * 64;

  // ---------------- stage: cs -> state tile in LDS (4 threads/row) -------
  {
    const int rl = tid >> 2;          // local row 0..63
    const int s  = tid & 3;           // 4 threads/row: covers e in [64s,64s+64)
    const int r  = row0 + rl;
    float4 ca, cb, sa, sb;            // cc[0..3], cc[4..7], ss[0..3], ss[4..7]
    if (r < B) {
      const float4* ip = (const float4*)(cs + (size_t)r * 16);
      ca = ip[0]; cb = ip[1]; sa = ip[2]; sb = ip[3];
    } else {
      ca = cb = sa = sb = (float4){0.f, 0.f, 0.f, 0.f};
    }
    // qubits 0,1 from s bits (b0 = s&2, b1 = s&1)
    float q0 = (s & 2) ? sa.x : ca.x;
    float q1 = (s & 1) ? sa.y : ca.y;
    float p01 = q0 * q1;
    // A8 over qubits 2,3,4 (index it = b2b3b4)
    float A8[8];
    {
      float c2 = ca.z, s2 = sa.z, c3 = ca.w, s3 = sa.w, c4 = cb.x, s4 = sb.x;
      float p23[4];
      p23[0] = c2 * c3; p23[1] = c2 * s3; p23[2] = s2 * c3; p23[3] = s2 * s3;
#pragma unroll
      for (int m = 0; m < 4; m++) {
        A8[2*m]   = p01 * p23[m] * c4;
        A8[2*m+1] = p01 * p23[m] * s4;
      }
    }
    // L8 over qubits 5,6,7 (index j = b5b6b7)
    float L8[8];
    {
      float c5 = cb.y, s5 = sb.y, c6 = cb.z, s6 = sb.z, c7 = cb.w, s7 = sb.w;
      float p56[4];
      p56[0] = c5 * c6; p56[1] = c5 * s6; p56[2] = s5 * c6; p56[3] = s5 * s6;
#pragma unroll
      for (int m = 0; m < 4; m++) {
        L8[2*m]   = p56[m] * c7;
        L8[2*m+1] = p56[m] * s7;
      }
    }
    // write 8 groups of 16B (64 bf16 = this thread's quarter of the row)
#pragma unroll
    for (int it = 0; it < 8; it++) {
      float ah = A8[it];                   // static index
      union { u16 h8[8]; uint4 u4; } pk;
#pragma unroll
      for (int j = 0; j < 8; j++) {
        __hip_bfloat16 bv = __float2bfloat16(ah * L8[j]);
        pk.h8[j] = *(u16*)&bv;
      }
      u32 byte = (u32)(rl * 512 + (s * 8 + it) * 16) ^ (u32)((rl & 7) << 4);
      *(uint4*)((char*)st + byte) = pk.u4;
    }
  }
  __syncthreads();

  // ---------------- wave/tile decomposition (R2's passed shape) ----------
  const int lane = tid & 63;
  const int wn   = tid >> 6;      // 0..3 -> N slice (all 64 rows per wave)
  const int lr   = lane & 15;
  const int lg   = lane >> 4;

  f4v acc[4][4];                  // SHARED accumulator for GEMM A and B

  // ---------------- GEMM A: f = relu(state @ W3 + b3) ----------------
#pragma unroll
  for (int nt = 0; nt < 4; nt++)
#pragma unroll
    for (int mt = 0; mt < 4; mt++) acc[nt][mt] = (f4v){0.f, 0.f, 0.f, 0.f};

  for (int kk = 0; kk < 8; kk++) {
    s8v a[4];
#pragma unroll
    for (int mt = 0; mt < 4; mt++) {
      int row = mt * 16 + lr;
      u32 byte = (u32)(row * 512 + kk * 64 + lg * 16) ^ (u32)((row & 7) << 4);
      a[mt] = *(const s8v*)((const char*)st + byte);
    }
#pragma unroll
    for (int nt = 0; nt < 4; nt++) {
      int ntg = wn * 4 + nt;
      s8v b = ((const s8v*)w3f)[(ntg * 8 + kk) * 64 + lane];
#pragma unroll
      for (int mt = 0; mt < 4; mt++)
        acc[nt][mt] = __builtin_amdgcn_mfma_f32_16x16x32_bf16(a[mt], b, acc[nt][mt], 0, 0, 0);
    }
  }
  __syncthreads();                 // all state reads complete before overwrite

  // f (bf16) overwrites state tile in place
#pragma unroll
  for (int nt = 0; nt < 4; nt++) {
    int col = wn * 64 + nt * 16 + lr;
    float bias = b3v[col];
#pragma unroll
    for (int mt = 0; mt < 4; mt++) {
#pragma unroll
      for (int i = 0; i < 4; i++) {
        int row = mt * 16 + lg * 4 + i;
        float v = fmaxf(acc[nt][mt][i] + bias, 0.f);
        __hip_bfloat16 bv = __float2bfloat16(v);
        u32 byte = (u32)(row * 512 + col * 2) ^ (u32)((row & 7) << 4);
        *(u16*)((char*)st + byte) = *(u16*)&bv;
      }
    }
  }
  __syncthreads();

  // ---------------- GEMM B: out = f @ W4 + b4 (two 64-col chunks) -------
#pragma unroll 1
  for (int nh = 0; nh < 2; nh++) {
    const int nbase = wn * 128 + nh * 64;
#pragma unroll
    for (int nt = 0; nt < 4; nt++)
#pragma unroll
      for (int mt = 0; mt < 4; mt++) acc[nt][mt] = (f4v){0.f, 0.f, 0.f, 0.f};

    for (int kk = 0; kk < 8; kk++) {
      s8v a[4];
#pragma unroll
      for (int mt = 0; mt < 4; mt++) {
        int row = mt * 16 + lr;
        u32 byte = (u32)(row * 512 + kk * 64 + lg * 16) ^ (u32)((row & 7) << 4);
        a[mt] = *(const s8v*)((const char*)st + byte);
      }
#pragma unroll
      for (int nt = 0; nt < 4; nt++) {
        int ntg = (nbase >> 4) + nt;
        s8v b = ((const s8v*)w4f)[(ntg * 8 + kk) * 64 + lane];
#pragma unroll
        for (int mt = 0; mt < 4; mt++)
          acc[nt][mt] = __builtin_amdgcn_mfma_f32_16x16x32_bf16(a[mt], b, acc[nt][mt], 0, 0, 0);
      }
    }
    // store fp32 + bias
#pragma unroll
    for (int nt = 0; nt < 4; nt++) {
      int col = nbase + nt * 16 + lr;
      float bias = b4v[col];
#pragma unroll
      for (int mt = 0; mt < 4; mt++) {
        int rowg = row0 + mt * 16 + lg * 4;
        if (rowg + 3 < B) {
          float* op = out + (size_t)rowg * 512 + col;
          op[0]    = acc[nt][mt][0] + bias;
          op[512]  = acc[nt][mt][1] + bias;
          op[1024] = acc[nt][mt][2] + bias;
          op[1536] = acc[nt][mt][3] + bias;
        } else {
#pragma unroll
          for (int i = 0; i < 4; i++)
            if (rowg + i < B) out[(size_t)(rowg + i) * 512 + col] = acc[nt][mt][i] + bias;
        }
      }
    }
  }
}

extern "C" void kernel_launch(void* const* d_in, const int* in_sizes, int n_in,
                              void* d_out, int out_size, void* d_ws, size_t ws_size,
                              hipStream_t stream) {
  const float* x  = (const float*)d_in[0];
  const float* W1 = (const float*)d_in[1];
  const float* b1 = (const float*)d_in[2];
  const float* W2 = (const float*)d_in[3];
  const float* b2 = (const float*)d_in[4];
  const float* W3 = (const float*)d_in[5];
  const float* b3 = (const float*)d_in[6];
  const float* W4 = (const float*)d_in[7];
  const float* b4 = (const float*)d_in[8];
  float* out = (float*)d_out;
  const int B = in_sizes[0] / 8;

  u16*   w3f = (u16*)d_ws;                                        // 128 KB
  u16*   w4f = (u16*)((char*)d_ws + 131072);                      // 256 KB
  float* w1t = (float*)((char*)d_ws + 131072 + 262144);           //   8 KB
  float* w2c = (float*)((char*)d_ws + 131072 + 262144 + 8192);    //   8 KB
  float* cs  = (float*)((char*)d_ws + 131072 + 262144 + 16384);   // B*64 B

  prep_kernel<<<784, 256, 0, stream>>>(W1, W2, W3, W4, w3f, w4f, w1t, w2c);
  angle_kernel<<<(B + 255) / 256, 256, 0, stream>>>(x, b1, b2, w1t, w2c, cs, B);
  gemm_kernel<<<(B + 63) / 64, 256, 0, stream>>>(cs, b3, b4, w3f, w4f, out, B);
}